// Round 1
// baseline (3847.496 us; speedup 1.0000x reference)
//
#include <hip/hip_runtime.h>

namespace {

constexpr int N_NODES = 100000;
constexpr int N_EDGES = 1600000;
constexpr int HDIM = 128;
constexpr int CDIM = 18;

// ---------------- degree + coeff ----------------

__global__ __launch_bounds__(256) void deg_kernel(const int* __restrict__ src,
                                                  const int* __restrict__ dst,
                                                  int* __restrict__ deg_out,
                                                  int* __restrict__ deg_in, int E) {
    int i = blockIdx.x * blockDim.x + threadIdx.x;
    if (i < E) {
        atomicAdd(&deg_out[src[i]], 1);
        atomicAdd(&deg_in[dst[i]], 1);
    }
}

__global__ __launch_bounds__(256) void coeff_kernel(const int* __restrict__ deg_out,
                                                    const int* __restrict__ deg_in,
                                                    float* __restrict__ c_src,
                                                    float* __restrict__ c_dst, int n) {
    int i = blockIdx.x * blockDim.x + threadIdx.x;
    if (i < n) {
        int dov = deg_out[i];
        int div = deg_in[i];
        c_src[i] = dov > 0 ? rsqrtf((float)dov) : 0.0f;
        c_dst[i] = div > 0 ? rsqrtf((float)div) : 0.0f;
    }
}

// ---------------- GEMM (x @ W) * c_src[row] ----------------
// One block per node; x-row staged in LDS; thread f computes output feature f.
// W column access W[k*OUT + f] is coalesced across threads.

template <int IN, int OUT, int BLOCK>
__global__ __launch_bounds__(BLOCK) void gemm_scale_kernel(const float* __restrict__ x,
                                                           const float* __restrict__ W,
                                                           const float* __restrict__ c_src,
                                                           float* __restrict__ xws, int n) {
    __shared__ float xs[IN];
    int node = blockIdx.x;
    if (node >= n) return;
    int f = threadIdx.x;
    for (int k = f; k < IN; k += BLOCK) xs[k] = x[(long long)node * IN + k];
    __syncthreads();
    if (f < OUT) {
        float acc = 0.0f;
#pragma unroll
        for (int k = 0; k < IN; ++k) acc += xs[k] * W[k * OUT + f];
        xws[(long long)node * OUT + f] = acc * c_src[node];
    }
}

// ---------------- edge scatter: agg[dst] += xws[src] ----------------
// TPE threads per edge (power of 2 >= OUT). Lanes within an edge cover
// consecutive features -> coalesced gather + coalesced atomic row add.

template <int OUT, int LOG2TPE>
__global__ __launch_bounds__(256) void scatter_kernel(const int* __restrict__ src,
                                                      const int* __restrict__ dst,
                                                      const float* __restrict__ xws,
                                                      float* __restrict__ agg, int E) {
    long long idx = (long long)blockIdx.x * blockDim.x + threadIdx.x;
    int e = (int)(idx >> LOG2TPE);
    int f = (int)(idx & ((1 << LOG2TPE) - 1));
    if (e < E && f < OUT) {
        int s = src[e];
        int d = dst[e];
        atomicAdd(&agg[(long long)d * OUT + f], xws[(long long)s * OUT + f]);
    }
}

// ---------------- epilogue: h = relu(agg * c_dst + b) ----------------

template <int OUT, bool RELU>
__global__ __launch_bounds__(256) void finish_kernel(float* __restrict__ agg,
                                                     const float* __restrict__ c_dst,
                                                     const float* __restrict__ b,
                                                     float* __restrict__ h, int n) {
    int idx = blockIdx.x * blockDim.x + threadIdx.x;
    if (idx < n * OUT) {
        int node = idx / OUT;
        int f = idx - node * OUT;
        float v = agg[idx] * c_dst[node] + b[f];
        h[idx] = RELU ? fmaxf(v, 0.0f) : v;
    }
}

inline size_t align_up(size_t x, size_t a) { return (x + a - 1) & ~(a - 1); }

}  // namespace

extern "C" void kernel_launch(void* const* d_in, const int* in_sizes, int n_in,
                              void* d_out, int out_size, void* d_ws, size_t ws_size,
                              hipStream_t stream) {
    const float* features = (const float*)d_in[0];
    const int* edge_src = (const int*)d_in[1];
    const int* edge_dst = (const int*)d_in[2];
    const float* W1 = (const float*)d_in[3];
    const float* b1 = (const float*)d_in[4];
    const float* W2 = (const float*)d_in[5];
    const float* b2 = (const float*)d_in[6];
    const float* W3 = (const float*)d_in[7];
    const float* b3 = (const float*)d_in[8];
    const float* W4 = (const float*)d_in[9];
    const float* b4 = (const float*)d_in[10];
    const float* W5 = (const float*)d_in[11];
    const float* b5 = (const float*)d_in[12];
    float* out = (float*)d_out;

    const int N = N_NODES;
    const int E = N_EDGES;

    // ---- workspace layout ----
    char* base = (char*)d_ws;
    size_t off = 0;
    auto take = [&](size_t bytes) {
        size_t o = off;
        off = align_up(off + bytes, 256);
        return (void*)(base + o);
    };
    int* deg_out = (int*)take(N * sizeof(int));
    int* deg_in = (int*)take(N * sizeof(int));
    float* c_src = (float*)take(N * sizeof(float));
    float* c_dst = (float*)take(N * sizeof(float));
    float* bufA = (float*)take((size_t)N * HDIM * sizeof(float));
    float* bufB = (float*)take((size_t)N * HDIM * sizeof(float));
    (void)ws_size;

    // ---- degrees + normalization coeffs (graph-only; once per call) ----
    hipMemsetAsync(deg_out, 0, 2 * align_up(N * sizeof(int), 256), stream);
    deg_kernel<<<(E + 255) / 256, 256, 0, stream>>>(edge_src, edge_dst, deg_out, deg_in, E);
    coeff_kernel<<<(N + 255) / 256, 256, 0, stream>>>(deg_out, deg_in, c_src, c_dst, N);

    // ---- layer 1: features[N,6] -> bufB holds h1[N,128] ----
    gemm_scale_kernel<6, HDIM, 128><<<N, 128, 0, stream>>>(features, W1, c_src, bufA, N);
    hipMemsetAsync(bufB, 0, (size_t)N * HDIM * sizeof(float), stream);
    {
        long long total = (long long)E << 7;
        scatter_kernel<HDIM, 7><<<(int)((total + 255) / 256), 256, 0, stream>>>(
            edge_src, edge_dst, bufA, bufB, E);
    }
    finish_kernel<HDIM, true><<<(N * HDIM + 255) / 256, 256, 0, stream>>>(bufB, c_dst, b1, bufB, N);

    // ---- layers 2..4: h[N,128] -> h[N,128] ----
    const float* Ws[3] = {W2, W3, W4};
    const float* bs[3] = {b2, b3, b4};
    for (int l = 0; l < 3; ++l) {
        gemm_scale_kernel<HDIM, HDIM, 128><<<N, 128, 0, stream>>>(bufB, Ws[l], c_src, bufA, N);
        hipMemsetAsync(bufB, 0, (size_t)N * HDIM * sizeof(float), stream);
        long long total = (long long)E << 7;
        scatter_kernel<HDIM, 7><<<(int)((total + 255) / 256), 256, 0, stream>>>(
            edge_src, edge_dst, bufA, bufB, E);
        finish_kernel<HDIM, true><<<(N * HDIM + 255) / 256, 256, 0, stream>>>(bufB, c_dst, bs[l],
                                                                              bufB, N);
    }

    // ---- layer 5: h[N,128] -> out[N,18], no relu ----
    gemm_scale_kernel<HDIM, CDIM, 64><<<N, 64, 0, stream>>>(bufB, W5, c_src, bufA, N);
    // reuse bufB front as agg[N,18]
    hipMemsetAsync(bufB, 0, (size_t)N * CDIM * sizeof(float), stream);
    {
        long long total = (long long)E << 5;  // 32 threads per edge, 18 active
        scatter_kernel<CDIM, 5><<<(int)((total + 255) / 256), 256, 0, stream>>>(
            edge_src, edge_dst, bufA, bufB, E);
    }
    finish_kernel<CDIM, false><<<(N * CDIM + 255) / 256, 256, 0, stream>>>(bufB, c_dst, b5, out, N);
}

// Round 2
// 1076.012 us; speedup vs baseline: 3.5757x; 3.5757x over previous
//
#include <hip/hip_runtime.h>

namespace {

constexpr int N_NODES = 100000;   // divisible by 8/16/32 -> exact grids
constexpr int N_EDGES = 1600000;
constexpr int HDIM = 128;
constexpr int CDIM = 18;

using f4 = __attribute__((ext_vector_type(4))) float;

// ---------------- degree ----------------

__global__ __launch_bounds__(256) void deg_kernel(const int* __restrict__ src,
                                                  const int* __restrict__ dst,
                                                  int* __restrict__ deg_out,
                                                  int* __restrict__ deg_in, int E) {
    int i = blockIdx.x * blockDim.x + threadIdx.x;
    if (i < E) {
        atomicAdd(&deg_out[src[i]], 1);
        atomicAdd(&deg_in[dst[i]], 1);
    }
}

__global__ __launch_bounds__(256) void coeff_kernel(const int* __restrict__ deg_out,
                                                    const int* __restrict__ deg_in,
                                                    float* __restrict__ c_src,
                                                    float* __restrict__ c_dst, int n) {
    int i = blockIdx.x * blockDim.x + threadIdx.x;
    if (i < n) {
        int dov = deg_out[i];
        int div = deg_in[i];
        c_src[i] = dov > 0 ? rsqrtf((float)dov) : 0.0f;
        c_dst[i] = div > 0 ? rsqrtf((float)div) : 0.0f;
    }
}

// ---------------- exclusive scan deg_in -> row_ptr (single block) ----------------

__global__ __launch_bounds__(1024) void scan_kernel(const int* __restrict__ deg,
                                                    int* __restrict__ row_ptr, int n, int total) {
    __shared__ int s[1024];
    int t = threadIdx.x;
    int chunk = (n + 1023) / 1024;
    int beg = t * chunk;
    int end = min(n, beg + chunk);
    int sum = 0;
    for (int i = beg; i < end; ++i) sum += deg[i];
    s[t] = sum;
    __syncthreads();
    for (int off = 1; off < 1024; off <<= 1) {
        int v = (t >= off) ? s[t - off] : 0;
        __syncthreads();
        s[t] += v;
        __syncthreads();
    }
    int run = (t == 0) ? 0 : s[t - 1];
    for (int i = beg; i < end; ++i) {
        row_ptr[i] = run;
        run += deg[i];
    }
    if (t == 0) row_ptr[n] = total;
}

// ---------------- CSR fill (order within a row is arbitrary; sum tolerates) ----------------

__global__ __launch_bounds__(256) void fill_kernel(const int* __restrict__ src,
                                                   const int* __restrict__ dst,
                                                   const int* __restrict__ row_ptr,
                                                   int* __restrict__ cnt,
                                                   int* __restrict__ csr_src, int E) {
    int e = blockIdx.x * blockDim.x + threadIdx.x;
    if (e < E) {
        int d = dst[e];
        int pos = row_ptr[d] + atomicAdd(&cnt[d], 1);
        csr_src[pos] = src[e];
    }
}

// ---------------- layer-1 front: agg6[v] = c_dst[v] * sum_in( c_src[s] * x[s] ) ----------------
// 8 lanes/node (6 active), 32 nodes per 256-block.

__global__ __launch_bounds__(256) void gather_feat6_kernel(const int* __restrict__ row_ptr,
                                                           const int* __restrict__ csr_src,
                                                           const float* __restrict__ feat,
                                                           const float* __restrict__ c_src,
                                                           const float* __restrict__ c_dst,
                                                           float* __restrict__ agg6, int n) {
    int node = blockIdx.x * 32 + (threadIdx.x >> 3);
    int lane = threadIdx.x & 7;
    if (node >= n || lane >= 6) return;
    int beg = row_ptr[node], end = row_ptr[node + 1];
    float acc = 0.0f;
    for (int i = beg; i < end; ++i) {
        int s = csr_src[i];
        acc += feat[s * 6 + lane] * c_src[s];
    }
    agg6[node * 6 + lane] = acc * c_dst[node];
}

// ---------------- layer-1 back: h1 = relu(agg6 @ W1 + b1) ----------------
// NT nodes per 128-thread block; thread f holds the 6 W-column values in regs.

template <int NT>
__global__ __launch_bounds__(128) void gemm6_kernel(const float* __restrict__ agg6,
                                                    const float* __restrict__ W,
                                                    const float* __restrict__ bias,
                                                    float* __restrict__ h, int n) {
    __shared__ float xs[NT][6];
    int f = threadIdx.x;
    int base = blockIdx.x * NT;
    for (int idx = f; idx < NT * 6; idx += 128) {
        int j = idx / 6, k = idx - j * 6;
        int node = base + j;
        xs[j][k] = (node < n) ? agg6[node * 6 + k] : 0.0f;
    }
    __syncthreads();
    float w[6];
#pragma unroll
    for (int k = 0; k < 6; ++k) w[k] = W[k * HDIM + f];
    float bv = bias[f];
    for (int j = 0; j < NT; ++j) {
        int node = base + j;
        if (node >= n) break;
        float acc = bv;
#pragma unroll
        for (int k = 0; k < 6; ++k) acc += xs[j][k] * w[k];
        h[node * HDIM + f] = fmaxf(acc, 0.0f);
    }
}

// ---------------- hidden GEMM: xw = (h @ W) * c_src  [128 -> 128] ----------------
// NT nodes per 128-thread block; x rows in LDS; W column value reused across NT nodes.

template <int NT>
__global__ __launch_bounds__(128) void gemm128_kernel(const float* __restrict__ h,
                                                      const float* __restrict__ W,
                                                      const float* __restrict__ c_src,
                                                      float* __restrict__ xw, int n) {
    __shared__ float xs[NT][HDIM];
    int f = threadIdx.x;
    int base = blockIdx.x * NT;
#pragma unroll
    for (int j = 0; j < NT; ++j) {
        int node = base + j;
        xs[j][f] = (node < n) ? h[(long long)node * HDIM + f] : 0.0f;
    }
    __syncthreads();
    float acc[NT];
#pragma unroll
    for (int j = 0; j < NT; ++j) acc[j] = 0.0f;
    for (int k = 0; k < HDIM; ++k) {
        float wv = W[k * HDIM + f];
#pragma unroll
        for (int j = 0; j < NT; ++j) acc[j] += xs[j][k] * wv;
    }
#pragma unroll
    for (int j = 0; j < NT; ++j) {
        int node = base + j;
        if (node < n) xw[(long long)node * HDIM + f] = acc[j] * c_src[node];
    }
}

// ---------------- hidden gather: h[v] = relu(c_dst[v] * sum_in(xw[s]) + b) ----------------
// 32 lanes/node, float4/lane, 8 nodes per 256-block, edge loop unrolled x2.

template <bool RELU>
__global__ __launch_bounds__(256) void gather128_kernel(const int* __restrict__ row_ptr,
                                                        const int* __restrict__ csr_src,
                                                        const float* __restrict__ xw,
                                                        const float* __restrict__ c_dst,
                                                        const float* __restrict__ bias,
                                                        float* __restrict__ out, int n) {
    int node = blockIdx.x * 8 + (threadIdx.x >> 5);
    int lane = threadIdx.x & 31;
    if (node >= n) return;
    int beg = row_ptr[node], end = row_ptr[node + 1];
    const f4* xw4 = (const f4*)xw;
    f4 acc0 = {0.f, 0.f, 0.f, 0.f};
    f4 acc1 = {0.f, 0.f, 0.f, 0.f};
    int i = beg;
    for (; i + 2 <= end; i += 2) {
        int s0 = csr_src[i];
        int s1 = csr_src[i + 1];
        acc0 += xw4[s0 * 32 + lane];
        acc1 += xw4[s1 * 32 + lane];
    }
    if (i < end) {
        int s0 = csr_src[i];
        acc0 += xw4[s0 * 32 + lane];
    }
    f4 r = acc0 + acc1;
    float cd = c_dst[node];
    f4 bb = ((const f4*)bias)[lane];
    r = r * cd + bb;
    if (RELU) {
#pragma unroll
        for (int q = 0; q < 4; ++q) r[q] = fmaxf(r[q], 0.0f);
    }
    ((f4*)out)[node * 32 + lane] = r;
}

// ---------------- output GEMM: xw18 = (h @ W5) * c_src  [128 -> 18] ----------------
// 32 lanes/node (18 active), h row staged in LDS, 8 nodes per 256-block.

__global__ __launch_bounds__(256) void gemm_out18_kernel(const float* __restrict__ h,
                                                         const float* __restrict__ W5,
                                                         const float* __restrict__ c_src,
                                                         float* __restrict__ xw18, int n) {
    __shared__ float hs[8][HDIM];
    int g = threadIdx.x >> 5;
    int lane = threadIdx.x & 31;
    int node = blockIdx.x * 8 + g;  // N % 8 == 0 -> always valid
    const f4* hrow = (const f4*)&h[(long long)node * HDIM];
    f4* hsg = (f4*)hs[g];
    hsg[lane] = hrow[lane];  // 32 lanes x 16B = full 128-float row
    __syncthreads();
    if (lane < CDIM) {
        float acc = 0.0f;
        for (int k = 0; k < HDIM; ++k) acc += hs[g][k] * W5[k * CDIM + lane];
        xw18[node * CDIM + lane] = acc * c_src[node];
    }
}

// ---------------- output gather: out = c_dst * sum_in(xw18) + b5 ----------------

__global__ __launch_bounds__(256) void gather18_kernel(const int* __restrict__ row_ptr,
                                                       const int* __restrict__ csr_src,
                                                       const float* __restrict__ xw18,
                                                       const float* __restrict__ c_dst,
                                                       const float* __restrict__ b5,
                                                       float* __restrict__ out, int n) {
    int node = blockIdx.x * 8 + (threadIdx.x >> 5);
    int lane = threadIdx.x & 31;
    if (node >= n || lane >= CDIM) return;
    int beg = row_ptr[node], end = row_ptr[node + 1];
    float acc0 = 0.0f, acc1 = 0.0f;
    int i = beg;
    for (; i + 2 <= end; i += 2) {
        acc0 += xw18[csr_src[i] * CDIM + lane];
        acc1 += xw18[csr_src[i + 1] * CDIM + lane];
    }
    if (i < end) acc0 += xw18[csr_src[i] * CDIM + lane];
    out[node * CDIM + lane] = (acc0 + acc1) * c_dst[node] + b5[lane];
}

inline size_t align_up(size_t x, size_t a) { return (x + a - 1) & ~(a - 1); }

}  // namespace

extern "C" void kernel_launch(void* const* d_in, const int* in_sizes, int n_in,
                              void* d_out, int out_size, void* d_ws, size_t ws_size,
                              hipStream_t stream) {
    const float* features = (const float*)d_in[0];
    const int* edge_src = (const int*)d_in[1];
    const int* edge_dst = (const int*)d_in[2];
    const float* W1 = (const float*)d_in[3];
    const float* b1 = (const float*)d_in[4];
    const float* W2 = (const float*)d_in[5];
    const float* b2 = (const float*)d_in[6];
    const float* W3 = (const float*)d_in[7];
    const float* b3 = (const float*)d_in[8];
    const float* W4 = (const float*)d_in[9];
    const float* b4 = (const float*)d_in[10];
    const float* W5 = (const float*)d_in[11];
    const float* b5 = (const float*)d_in[12];
    float* out = (float*)d_out;

    const int N = N_NODES;
    const int E = N_EDGES;

    // ---- workspace layout ----
    char* base = (char*)d_ws;
    size_t off = 0;
    auto take = [&](size_t bytes) {
        size_t o = off;
        off = align_up(off + bytes, 256);
        return (void*)(base + o);
    };
    int* deg_out = (int*)take(N * sizeof(int));  // reused as CSR fill counter
    int* deg_in = (int*)take(N * sizeof(int));
    float* c_src = (float*)take(N * sizeof(float));
    float* c_dst = (float*)take(N * sizeof(float));
    int* row_ptr = (int*)take((N + 1) * sizeof(int));
    int* csr_src = (int*)take((size_t)E * sizeof(int));
    float* agg6 = (float*)take((size_t)N * 6 * sizeof(float));
    float* bufA = (float*)take((size_t)N * HDIM * sizeof(float));  // xw
    float* bufB = (float*)take((size_t)N * HDIM * sizeof(float));  // h
    (void)ws_size;

    // ---- graph preprocessing (per call; graph tensors are inputs) ----
    hipMemsetAsync(deg_out, 0, N * sizeof(int), stream);
    hipMemsetAsync(deg_in, 0, N * sizeof(int), stream);
    deg_kernel<<<(E + 255) / 256, 256, 0, stream>>>(edge_src, edge_dst, deg_out, deg_in, E);
    coeff_kernel<<<(N + 255) / 256, 256, 0, stream>>>(deg_out, deg_in, c_src, c_dst, N);
    scan_kernel<<<1, 1024, 0, stream>>>(deg_in, row_ptr, N, E);
    hipMemsetAsync(deg_out, 0, N * sizeof(int), stream);  // reuse as cnt
    fill_kernel<<<(E + 255) / 256, 256, 0, stream>>>(edge_src, edge_dst, row_ptr, deg_out, csr_src,
                                                     E);

    // ---- layer 1 (aggregate-first on 6 features, then 6->128 GEMM + bias + relu) ----
    gather_feat6_kernel<<<N / 32, 256, 0, stream>>>(row_ptr, csr_src, features, c_src, c_dst, agg6,
                                                    N);
    gemm6_kernel<16><<<N / 16, 128, 0, stream>>>(agg6, W1, b1, bufB, N);

    // ---- layers 2..4: xw = (h@W)*c_src ; h = relu(c_dst*gather(xw) + b) ----
    const float* Ws[3] = {W2, W3, W4};
    const float* bs[3] = {b2, b3, b4};
    for (int l = 0; l < 3; ++l) {
        gemm128_kernel<8><<<N / 8, 128, 0, stream>>>(bufB, Ws[l], c_src, bufA, N);
        gather128_kernel<true><<<N / 8, 256, 0, stream>>>(row_ptr, csr_src, bufA, c_dst, bs[l],
                                                          bufB, N);
    }

    // ---- layer 5: xw18 = (h@W5)*c_src ; out = c_dst*gather(xw18) + b5 ----
    gemm_out18_kernel<<<N / 8, 256, 0, stream>>>(bufB, W5, c_src, bufA, N);
    gather18_kernel<<<N / 8, 256, 0, stream>>>(row_ptr, csr_src, bufA, c_dst, b5, out, N);
}

// Round 3
// 911.326 us; speedup vs baseline: 4.2219x; 1.1807x over previous
//
#include <hip/hip_runtime.h>

namespace {

constexpr int N_NODES = 100000;   // divisible by 8/16/32 -> exact grids
constexpr int N_EDGES = 1600000;
constexpr int HDIM = 128;
constexpr int CDIM = 18;
constexpr int NB = (N_NODES + 255) / 256;  // scan blocks = 391 (<=512)

using f4 = __attribute__((ext_vector_type(4))) float;

// ---------------- degree ----------------

__global__ __launch_bounds__(256) void deg_kernel(const int* __restrict__ src,
                                                  const int* __restrict__ dst,
                                                  int* __restrict__ deg_out,
                                                  int* __restrict__ deg_in, int E) {
    int i = blockIdx.x * blockDim.x + threadIdx.x;
    if (i < E) {
        atomicAdd(&deg_out[src[i]], 1);
        atomicAdd(&deg_in[dst[i]], 1);
    }
}

__global__ __launch_bounds__(256) void coeff_kernel(const int* __restrict__ deg_out,
                                                    const int* __restrict__ deg_in,
                                                    float* __restrict__ c_src,
                                                    float* __restrict__ c_dst, int n) {
    int i = blockIdx.x * blockDim.x + threadIdx.x;
    if (i < n) {
        int dov = deg_out[i];
        int div = deg_in[i];
        c_src[i] = dov > 0 ? rsqrtf((float)dov) : 0.0f;
        c_dst[i] = div > 0 ? rsqrtf((float)div) : 0.0f;
    }
}

// ---------------- parallel exclusive scan: deg_in -> row_ptr ----------------

__global__ __launch_bounds__(256) void scan_partial_kernel(const int* __restrict__ deg,
                                                           int* __restrict__ blk_sum, int n) {
    __shared__ int s[256];
    int i = blockIdx.x * 256 + threadIdx.x;
    s[threadIdx.x] = (i < n) ? deg[i] : 0;
    __syncthreads();
    for (int off = 128; off > 0; off >>= 1) {
        if (threadIdx.x < off) s[threadIdx.x] += s[threadIdx.x + off];
        __syncthreads();
    }
    if (threadIdx.x == 0) blk_sum[blockIdx.x] = s[0];
}

__global__ __launch_bounds__(512) void scan_blocksums_kernel(int* __restrict__ blk_sum, int nb) {
    __shared__ int s[512];
    int t = threadIdx.x;
    s[t] = (t < nb) ? blk_sum[t] : 0;
    __syncthreads();
    for (int off = 1; off < 512; off <<= 1) {
        int v = (t >= off) ? s[t - off] : 0;
        __syncthreads();
        s[t] += v;
        __syncthreads();
    }
    if (t < nb) blk_sum[t] = (t == 0) ? 0 : s[t - 1];  // exclusive, in place
}

__global__ __launch_bounds__(256) void scan_final_kernel(const int* __restrict__ deg,
                                                         const int* __restrict__ blk_off,
                                                         int* __restrict__ row_ptr, int n,
                                                         int total) {
    __shared__ int s[256];
    int b = blockIdx.x;
    int t = threadIdx.x;
    int i = b * 256 + t;
    int v = (i < n) ? deg[i] : 0;
    s[t] = v;
    __syncthreads();
    for (int off = 1; off < 256; off <<= 1) {
        int u = (t >= off) ? s[t - off] : 0;
        __syncthreads();
        s[t] += u;
        __syncthreads();
    }
    if (i < n) row_ptr[i] = blk_off[b] + s[t] - v;  // exclusive
    if (i == 0) row_ptr[n] = total;
}

// ---------------- CSR fill (order within a row is arbitrary; sum tolerates) ----------------

__global__ __launch_bounds__(256) void fill_kernel(const int* __restrict__ src,
                                                   const int* __restrict__ dst,
                                                   const int* __restrict__ row_ptr,
                                                   int* __restrict__ cnt,
                                                   int* __restrict__ csr_src, int E) {
    int e = blockIdx.x * blockDim.x + threadIdx.x;
    if (e < E) {
        int d = dst[e];
        int pos = row_ptr[d] + atomicAdd(&cnt[d], 1);
        csr_src[pos] = src[e];
    }
}

// ---------------- layer-1 front: agg6[v] = c_dst[v] * sum_in( c_src[s] * x[s] ) ----------------

__global__ __launch_bounds__(256) void gather_feat6_kernel(const int* __restrict__ row_ptr,
                                                           const int* __restrict__ csr_src,
                                                           const float* __restrict__ feat,
                                                           const float* __restrict__ c_src,
                                                           const float* __restrict__ c_dst,
                                                           float* __restrict__ agg6, int n) {
    int node = blockIdx.x * 32 + (threadIdx.x >> 3);
    int lane = threadIdx.x & 7;
    if (node >= n || lane >= 6) return;
    int beg = row_ptr[node], end = row_ptr[node + 1];
    float acc = 0.0f;
    for (int i = beg; i < end; ++i) {
        int s = csr_src[i];
        acc += feat[s * 6 + lane] * c_src[s];
    }
    agg6[node * 6 + lane] = acc * c_dst[node];
}

// ---------------- layer-1 back: h1 = relu(agg6 @ W1 + b1) ----------------

template <int NT>
__global__ __launch_bounds__(128) void gemm6_kernel(const float* __restrict__ agg6,
                                                    const float* __restrict__ W,
                                                    const float* __restrict__ bias,
                                                    float* __restrict__ h, int n) {
    __shared__ float xs[NT][6];
    int f = threadIdx.x;
    int base = blockIdx.x * NT;
    for (int idx = f; idx < NT * 6; idx += 128) {
        int j = idx / 6, k = idx - j * 6;
        int node = base + j;
        xs[j][k] = (node < n) ? agg6[node * 6 + k] : 0.0f;
    }
    __syncthreads();
    float w[6];
#pragma unroll
    for (int k = 0; k < 6; ++k) w[k] = W[k * HDIM + f];
    float bv = bias[f];
    for (int j = 0; j < NT; ++j) {
        int node = base + j;
        if (node >= n) break;
        float acc = bv;
#pragma unroll
        for (int k = 0; k < 6; ++k) acc += xs[j][k] * w[k];
        h[node * HDIM + f] = fmaxf(acc, 0.0f);
    }
}

// ---------------- hidden GEMM: xw = (h @ W) * c_src  [128 -> 128] ----------------
// 64-thread blocks; thread f computes features {f, f+64} for 16 nodes.
// Per k4 step: 16 ds_read_b128 (192 cyc) vs 128 v_fma (256 cyc) -> FMA-bound.

__global__ __launch_bounds__(64) void gemm128_kernel(const float* __restrict__ h,
                                                     const float* __restrict__ W,
                                                     const float* __restrict__ c_src,
                                                     float* __restrict__ xw, int n) {
    __shared__ f4 xs[16][32];
    int f = threadIdx.x;  // 0..63
    long long base = (long long)blockIdx.x * 16;
    const f4* h4 = (const f4*)h;
#pragma unroll
    for (int r = 0; r < 8; ++r) {
        int idx = r * 64 + f;
        int j = idx >> 5, q = idx & 31;
        xs[j][q] = h4[(base + j) * 32 + q];
    }
    __syncthreads();
    float acc0[16], acc1[16];
#pragma unroll
    for (int j = 0; j < 16; ++j) {
        acc0[j] = 0.0f;
        acc1[j] = 0.0f;
    }
    const float* Wf = W + f;
    for (int k4 = 0; k4 < 32; ++k4) {
        int kb = k4 * 4 * HDIM;
        float w00 = Wf[kb];
        float w01 = Wf[kb + HDIM];
        float w02 = Wf[kb + 2 * HDIM];
        float w03 = Wf[kb + 3 * HDIM];
        float w10 = Wf[kb + 64];
        float w11 = Wf[kb + HDIM + 64];
        float w12 = Wf[kb + 2 * HDIM + 64];
        float w13 = Wf[kb + 3 * HDIM + 64];
#pragma unroll
        for (int j = 0; j < 16; ++j) {
            f4 x = xs[j][k4];
            acc0[j] += x.x * w00;
            acc0[j] += x.y * w01;
            acc0[j] += x.z * w02;
            acc0[j] += x.w * w03;
            acc1[j] += x.x * w10;
            acc1[j] += x.y * w11;
            acc1[j] += x.z * w12;
            acc1[j] += x.w * w13;
        }
    }
#pragma unroll
    for (int j = 0; j < 16; ++j) {
        long long node = base + j;
        float cs = c_src[node];
        xw[node * HDIM + f] = acc0[j] * cs;
        xw[node * HDIM + 64 + f] = acc1[j] * cs;
    }
}

// ---------------- hidden gather: h[v] = relu(c_dst[v] * sum_in(xw[s]) + b) ----------------

template <bool RELU>
__global__ __launch_bounds__(256) void gather128_kernel(const int* __restrict__ row_ptr,
                                                        const int* __restrict__ csr_src,
                                                        const float* __restrict__ xw,
                                                        const float* __restrict__ c_dst,
                                                        const float* __restrict__ bias,
                                                        float* __restrict__ out, int n) {
    int node = blockIdx.x * 8 + (threadIdx.x >> 5);
    int lane = threadIdx.x & 31;
    if (node >= n) return;
    int beg = row_ptr[node], end = row_ptr[node + 1];
    const f4* xw4 = (const f4*)xw;
    f4 acc0 = {0.f, 0.f, 0.f, 0.f};
    f4 acc1 = {0.f, 0.f, 0.f, 0.f};
    int i = beg;
    for (; i + 2 <= end; i += 2) {
        int s0 = csr_src[i];
        int s1 = csr_src[i + 1];
        acc0 += xw4[s0 * 32 + lane];
        acc1 += xw4[s1 * 32 + lane];
    }
    if (i < end) {
        int s0 = csr_src[i];
        acc0 += xw4[s0 * 32 + lane];
    }
    f4 r = acc0 + acc1;
    float cd = c_dst[node];
    f4 bb = ((const f4*)bias)[lane];
    r = r * cd + bb;
    if (RELU) {
#pragma unroll
        for (int q = 0; q < 4; ++q) r[q] = fmaxf(r[q], 0.0f);
    }
    ((f4*)out)[node * 32 + lane] = r;
}

// ---------------- output GEMM: xw18 = (h @ W5) * c_src  [128 -> 18] ----------------

__global__ __launch_bounds__(256) void gemm_out18_kernel(const float* __restrict__ h,
                                                         const float* __restrict__ W5,
                                                         const float* __restrict__ c_src,
                                                         float* __restrict__ xw18, int n) {
    __shared__ float hs[8][HDIM];
    int g = threadIdx.x >> 5;
    int lane = threadIdx.x & 31;
    int node = blockIdx.x * 8 + g;  // N % 8 == 0 -> always valid
    const f4* hrow = (const f4*)&h[(long long)node * HDIM];
    f4* hsg = (f4*)hs[g];
    hsg[lane] = hrow[lane];  // 32 lanes x 16B = full 128-float row
    __syncthreads();
    if (lane < CDIM) {
        float acc = 0.0f;
        for (int k = 0; k < HDIM; ++k) acc += hs[g][k] * W5[k * CDIM + lane];
        xw18[node * CDIM + lane] = acc * c_src[node];
    }
}

// ---------------- output gather: out = c_dst * sum_in(xw18) + b5 ----------------

__global__ __launch_bounds__(256) void gather18_kernel(const int* __restrict__ row_ptr,
                                                       const int* __restrict__ csr_src,
                                                       const float* __restrict__ xw18,
                                                       const float* __restrict__ c_dst,
                                                       const float* __restrict__ b5,
                                                       float* __restrict__ out, int n) {
    int node = blockIdx.x * 8 + (threadIdx.x >> 5);
    int lane = threadIdx.x & 31;
    if (node >= n || lane >= CDIM) return;
    int beg = row_ptr[node], end = row_ptr[node + 1];
    float acc0 = 0.0f, acc1 = 0.0f;
    int i = beg;
    for (; i + 2 <= end; i += 2) {
        acc0 += xw18[csr_src[i] * CDIM + lane];
        acc1 += xw18[csr_src[i + 1] * CDIM + lane];
    }
    if (i < end) acc0 += xw18[csr_src[i] * CDIM + lane];
    out[node * CDIM + lane] = (acc0 + acc1) * c_dst[node] + b5[lane];
}

inline size_t align_up(size_t x, size_t a) { return (x + a - 1) & ~(a - 1); }

}  // namespace

extern "C" void kernel_launch(void* const* d_in, const int* in_sizes, int n_in,
                              void* d_out, int out_size, void* d_ws, size_t ws_size,
                              hipStream_t stream) {
    const float* features = (const float*)d_in[0];
    const int* edge_src = (const int*)d_in[1];
    const int* edge_dst = (const int*)d_in[2];
    const float* W1 = (const float*)d_in[3];
    const float* b1 = (const float*)d_in[4];
    const float* W2 = (const float*)d_in[5];
    const float* b2 = (const float*)d_in[6];
    const float* W3 = (const float*)d_in[7];
    const float* b3 = (const float*)d_in[8];
    const float* W4 = (const float*)d_in[9];
    const float* b4 = (const float*)d_in[10];
    const float* W5 = (const float*)d_in[11];
    const float* b5 = (const float*)d_in[12];
    float* out = (float*)d_out;

    const int N = N_NODES;
    const int E = N_EDGES;

    // ---- workspace layout ----
    char* base = (char*)d_ws;
    size_t off = 0;
    auto take = [&](size_t bytes) {
        size_t o = off;
        off = align_up(off + bytes, 256);
        return (void*)(base + o);
    };
    int* deg_out = (int*)take(N * sizeof(int));  // reused as CSR fill counter
    int* deg_in = (int*)take(N * sizeof(int));
    float* c_src = (float*)take(N * sizeof(float));
    float* c_dst = (float*)take(N * sizeof(float));
    int* row_ptr = (int*)take((N + 1) * sizeof(int));
    int* blk_sum = (int*)take(512 * sizeof(int));
    int* csr_src = (int*)take((size_t)E * sizeof(int));
    float* agg6 = (float*)take((size_t)N * 6 * sizeof(float));
    float* bufA = (float*)take((size_t)N * HDIM * sizeof(float));  // xw
    float* bufB = (float*)take((size_t)N * HDIM * sizeof(float));  // h
    (void)ws_size;

    // ---- graph preprocessing (per call; graph tensors are inputs) ----
    hipMemsetAsync(deg_out, 0, N * sizeof(int), stream);
    hipMemsetAsync(deg_in, 0, N * sizeof(int), stream);
    deg_kernel<<<(E + 255) / 256, 256, 0, stream>>>(edge_src, edge_dst, deg_out, deg_in, E);
    coeff_kernel<<<(N + 255) / 256, 256, 0, stream>>>(deg_out, deg_in, c_src, c_dst, N);
    scan_partial_kernel<<<NB, 256, 0, stream>>>(deg_in, blk_sum, N);
    scan_blocksums_kernel<<<1, 512, 0, stream>>>(blk_sum, NB);
    scan_final_kernel<<<NB, 256, 0, stream>>>(deg_in, blk_sum, row_ptr, N, E);
    hipMemsetAsync(deg_out, 0, N * sizeof(int), stream);  // reuse as cnt
    fill_kernel<<<(E + 255) / 256, 256, 0, stream>>>(edge_src, edge_dst, row_ptr, deg_out, csr_src,
                                                     E);

    // ---- layer 1 (aggregate-first on 6 features, then 6->128 GEMM + bias + relu) ----
    gather_feat6_kernel<<<N / 32, 256, 0, stream>>>(row_ptr, csr_src, features, c_src, c_dst, agg6,
                                                    N);
    gemm6_kernel<16><<<N / 16, 128, 0, stream>>>(agg6, W1, b1, bufB, N);

    // ---- layers 2..4: xw = (h@W)*c_src ; h = relu(c_dst*gather(xw) + b) ----
    const float* Ws[3] = {W2, W3, W4};
    const float* bs[3] = {b2, b3, b4};
    for (int l = 0; l < 3; ++l) {
        gemm128_kernel<<<N / 16, 64, 0, stream>>>(bufB, Ws[l], c_src, bufA, N);
        gather128_kernel<true><<<N / 8, 256, 0, stream>>>(row_ptr, csr_src, bufA, c_dst, bs[l],
                                                          bufB, N);
    }

    // ---- layer 5: xw18 = (h@W5)*c_src ; out = c_dst*gather(xw18) + b5 ----
    gemm_out18_kernel<<<N / 8, 256, 0, stream>>>(bufB, W5, c_src, bufA, N);
    gather18_kernel<<<N / 8, 256, 0, stream>>>(row_ptr, csr_src, bufA, c_dst, b5, out, N);
}